// Round 15
// baseline (383.270 us; speedup 1.0000x reference)
//
#include <hip/hip_runtime.h>
#include <hip/hip_bf16.h>
#include <math.h>

#define LB256 __launch_bounds__(256)

#define NB_SHIFT 8
#define NB_ROWS  (1 << NB_SHIFT)   // 256 rows per bucket
#define GA 1024                    // blocks for hist/scatter passes (4 blocks/CU)
#define TILE 2048                  // edges per sort tile
#define CBCAP 12288                // csr_build LDS stage capacity (seg ~8192±90)

// ---------------- hierarchical exclusive scan ----------------
template <int PT>
__global__ LB256 void gscan_sum(const int* __restrict__ a, int n, int* __restrict__ bsum) {
    int base = blockIdx.x * (256 * PT);
    int sum = 0;
    for (int i = threadIdx.x; i < 256 * PT; i += 256) {
        int idx = base + i;
        sum += (idx < n) ? a[idx] : 0;
    }
#pragma unroll
    for (int o = 32; o; o >>= 1) sum += __shfl_down(sum, o);
    __shared__ int ws[4];
    if ((threadIdx.x & 63) == 0) ws[threadIdx.x >> 6] = sum;
    __syncthreads();
    if (threadIdx.x == 0) bsum[blockIdx.x] = ws[0] + ws[1] + ws[2] + ws[3];
}

__global__ void gscan_offsets(const int* __restrict__ bsum, int nbk, int* __restrict__ boff) {
    int lane = threadIdx.x;
    int v = (lane < nbk) ? bsum[lane] : 0;
    int orig = v;
#pragma unroll
    for (int o = 1; o < 64; o <<= 1) {
        int u = __shfl_up(v, o);
        if (lane >= o) v += u;
    }
    if (lane < nbk) boff[lane] = v - orig;  // exclusive
}

template <int PT>
__global__ LB256 void gscan_scatter(const int* __restrict__ a, int n,
                                    const int* __restrict__ boff, int total,
                                    int* __restrict__ out1) {
    int base = blockIdx.x * (256 * PT);
    int idx0 = base + threadIdx.x * PT;
    int vals[PT];
    int s = 0;
#pragma unroll
    for (int k = 0; k < PT; ++k) {
        int id = idx0 + k;
        vals[k] = (id < n) ? a[id] : 0;
        s += vals[k];
    }
    int lane = threadIdx.x & 63, wid = threadIdx.x >> 6;
    int inc = s;
#pragma unroll
    for (int o = 1; o < 64; o <<= 1) {
        int u = __shfl_up(inc, o);
        if (lane >= o) inc += u;
    }
    __shared__ int wsum[4];
    if (lane == 63) wsum[wid] = inc;
    __syncthreads();
    int woff = 0;
    for (int i = 0; i < wid; ++i) woff += wsum[i];
    int excl = inc - s + woff + boff[blockIdx.x];
#pragma unroll
    for (int k = 0; k < PT; ++k) {
        int id = idx0 + k;
        if (id < n) out1[id] = excl;
        excl += vals[k];
    }
    if (blockIdx.x == 0 && threadIdx.x == 0) out1[n] = total;
}

// ---------------- CSR build (no global atomics) ----------------

__global__ LB256 void hist_kernel(const int* __restrict__ row, int E, int nb, int chunk,
                                  int* __restrict__ countmat) {
    __shared__ int lh[512];
    for (int b = threadIdx.x; b < 512; b += 256) lh[b] = 0;
    __syncthreads();
    int beg = blockIdx.x * chunk;
    int end = min(E, beg + chunk);
    for (int i = beg + threadIdx.x; i < end; i += 256)
        atomicAdd(&lh[row[i] >> NB_SHIFT], 1);
    __syncthreads();
    for (int b = threadIdx.x; b < nb; b += 256)
        countmat[b * gridDim.x + blockIdx.x] = lh[b];
}

// tile-ranked scatter: per 2048-edge tile, rank entries by bucket in LDS, then
// wave-coalesced write-out. entry u64 = bucket<<40 | rowlocal<<32 | wbits15<<17 | col
__global__ LB256 void sort_scatter_kernel(const int* __restrict__ row, const int* __restrict__ col,
                                          const float* __restrict__ w, const int* __restrict__ off,
                                          int E, int G, int chunk,
                                          unsigned long long* __restrict__ tmp) {
    __shared__ unsigned long long stage[TILE];
    __shared__ int lh[512];
    __shared__ int seg[512];
    __shared__ int gcur[512];
    __shared__ int wsum[4];
    int blk = blockIdx.x, tid = threadIdx.x;
    int beg = blk * chunk, end = min(E, beg + chunk);
    for (int b = tid; b < 512; b += 256) {
        gcur[b] = off[b * G + blk];
        lh[b] = 0;
    }
    __syncthreads();

    for (int tbase = beg; tbase < end; tbase += TILE) {
        int tcnt = min(TILE, end - tbase);
        int bk[8], sl[8];
        unsigned long long en[8];
#pragma unroll
        for (int k = 0; k < 8; ++k) {
            int e = tbase + k * 256 + tid;
            bk[k] = -1;
            if (e < end) {
                int r = row[e];
                int b = r >> NB_SHIFT;
                unsigned wb = (__float_as_uint(w[e]) + 0x8000u) >> 16;  // bf16 RN bits, w>=0
                en[k] = ((unsigned long long)b << 40) |
                        ((unsigned long long)(r & (NB_ROWS - 1)) << 32) |
                        (unsigned long long)((wb << 17) | (unsigned)col[e]);
                bk[k] = b;
                sl[k] = atomicAdd(&lh[b], 1);
            }
        }
        __syncthreads();
        // exclusive scan of lh[0..511] -> seg
        int c0 = lh[2 * tid], c1 = lh[2 * tid + 1];
        int tsum = c0 + c1;
        int lane = tid & 63, wid = tid >> 6;
        int inc = tsum;
#pragma unroll
        for (int o = 1; o < 64; o <<= 1) {
            int u = __shfl_up(inc, o);
            if (lane >= o) inc += u;
        }
        if (lane == 63) wsum[wid] = inc;
        __syncthreads();
        int woff = 0;
        for (int i = 0; i < wid; ++i) woff += wsum[i];
        int ex = inc - tsum + woff;
        seg[2 * tid] = ex;
        seg[2 * tid + 1] = ex + c0;
        __syncthreads();
        // place into stage ordered by bucket
#pragma unroll
        for (int k = 0; k < 8; ++k)
            if (bk[k] >= 0) stage[seg[bk[k]] + sl[k]] = en[k];
        __syncthreads();
        // coalesced write-out
        for (int p = tid; p < tcnt; p += 256) {
            unsigned long long ent = stage[p];
            int b = (int)(ent >> 40);
            tmp[gcur[b] + (p - seg[b])] = ent;
        }
        __syncthreads();
        for (int b = tid; b < 512; b += 256) {
            gcur[b] += lh[b];
            lh[b] = 0;
        }
        __syncthreads();
    }
}

// one block (512 threads) per 256-row bucket: histogram -> scan (first 4 waves)
// -> rowptr; then rank into LDS stage and write csr linearly (coalesced).
__global__ __launch_bounds__(512) void csr_build_kernel(const unsigned long long* __restrict__ tmp,
                                                        const int* __restrict__ off,
                                                        int G, int N, int E,
                                                        int* __restrict__ rowptr,
                                                        unsigned* __restrict__ csr) {
    __shared__ int lcnt[NB_ROWS];
    __shared__ int wsum[4];
    __shared__ unsigned stage[CBCAP];
    int b = blockIdx.x;
    int tid = threadIdx.x;
    int s0 = off[b * G];
    int e0 = off[(b + 1) * G];
    int seg = e0 - s0;
    int rbase = b << NB_SHIFT;

    if (tid < NB_ROWS) lcnt[tid] = 0;
    __syncthreads();
    for (int j = s0 + tid; j < e0; j += 512)
        atomicAdd(&lcnt[(int)((tmp[j] >> 32) & 0xFFu)], 1);
    __syncthreads();

    int val = 0, inc = 0;
    int lane = tid & 63, wid = tid >> 6;
    if (tid < NB_ROWS) {
        val = lcnt[tid];
        inc = val;
#pragma unroll
        for (int o = 1; o < 64; o <<= 1) {
            int u = __shfl_up(inc, o);
            if (lane >= o) inc += u;
        }
        if (lane == 63) wsum[wid] = inc;
    }
    __syncthreads();
    if (tid < NB_ROWS) {
        int woff = 0;
        for (int i = 0; i < wid; ++i) woff += wsum[i];
        int ex = inc - val + woff;
        int idx = rbase + tid;
        if (idx < N) rowptr[idx] = s0 + ex;
        lcnt[tid] = ex;  // cursors (bucket-local)
    }
    if (b == gridDim.x - 1 && tid == 0) rowptr[N] = E;
    __syncthreads();

    if (seg <= CBCAP) {
        for (int j = s0 + tid; j < e0; j += 512) {
            unsigned long long ent = tmp[j];
            int pos = atomicAdd(&lcnt[(int)((ent >> 32) & 0xFFu)], 1);
            stage[pos] = (unsigned)ent;
        }
        __syncthreads();
        for (int p = tid; p < seg; p += 512) csr[s0 + p] = stage[p];
    } else {  // overflow fallback (statistically unreachable)
        for (int j = s0 + tid; j < e0; j += 512) {
            unsigned long long ent = tmp[j];
            int pos = s0 + atomicAdd(&lcnt[(int)((ent >> 32) & 0xFFu)], 1);
            csr[pos] = (unsigned)ent;
        }
    }
}

// ---------------- per-layer kernels ----------------

// t (bf16) = h @ W^T, feature-split into halves of FH=min(FOUT,16)
template <int FIN, int FOUT>
__global__ LB256 void transform_kernel(const float* __restrict__ h, const float* __restrict__ W,
                                       __hip_bfloat16* __restrict__ t0,
                                       __hip_bfloat16* __restrict__ t1, int n) {
    constexpr int FH = (FOUT > 16) ? 16 : FOUT;
    int i = blockIdx.x * blockDim.x + threadIdx.x;
    if (i >= n * FOUT) return;
    int v = i / FOUT;
    int f = i % FOUT;
    float s = 0.0f;
#pragma unroll
    for (int k = 0; k < FIN; ++k) s = fmaf(h[v * FIN + k], W[f * FIN + k], s);
    __hip_bfloat16 bv = __float2bfloat16(s);
    if (f < FH) t0[v * FH + f] = bv;
    else        t1[v * FH + (f - FH)] = bv;
}

// gather-side aggregation; lane owns 4 features (one u64 = 4 bf16); GS=FH/4
// lanes per row-group. csr entry: (wbits15<<17)|col ; th: [N][GS] u64 words.
template <int FH, int FTOT>
__global__ LB256 void agg_half_kernel(const int* __restrict__ rowptr,
                                      const unsigned* __restrict__ csr,
                                      const unsigned long long* __restrict__ th,
                                      const float* __restrict__ b, int fo,
                                      float* __restrict__ h, int N) {
    constexpr int GS = FH / 4;        // lanes per row
    constexpr int RPB = 256 / GS;     // rows per block
    int g = threadIdx.x / GS;
    int l = threadIdx.x % GS;
    int v = blockIdx.x * RPB + g;
    if (v >= N) return;
    int beg = rowptr[v], end = rowptr[v + 1];
    float bf0 = b[fo + 4 * l + 0];
    float bf1 = b[fo + 4 * l + 1];
    float bf2 = b[fo + 4 * l + 2];
    float bf3 = b[fo + 4 * l + 3];
    float a0 = 0.f, a1 = 0.f, a2 = 0.f, a3 = 0.f;

    int j = beg;
    for (; j + 15 < end; j += 16) {
        unsigned e[16];
#pragma unroll
        for (int u = 0; u < 16; ++u) e[u] = __builtin_nontemporal_load(&csr[j + u]);
        unsigned long long tv[16];
#pragma unroll
        for (int u = 0; u < 16; ++u) tv[u] = th[(e[u] & 0x1FFFFu) * GS + l];
#pragma unroll
        for (int u = 0; u < 16; ++u) {
            float wv = __uint_as_float((e[u] & 0xFFFE0000u) >> 1);
            unsigned lo = (unsigned)tv[u], hi = (unsigned)(tv[u] >> 32);
            float m;
            m = fmaf(wv, __uint_as_float(lo << 16), bf0);          a0 += (m > 0.f) ? m : 0.01f * m;
            m = fmaf(wv, __uint_as_float(lo & 0xffff0000u), bf1);  a1 += (m > 0.f) ? m : 0.01f * m;
            m = fmaf(wv, __uint_as_float(hi << 16), bf2);          a2 += (m > 0.f) ? m : 0.01f * m;
            m = fmaf(wv, __uint_as_float(hi & 0xffff0000u), bf3);  a3 += (m > 0.f) ? m : 0.01f * m;
        }
    }
    for (; j < end; ++j) {
        unsigned e0 = __builtin_nontemporal_load(&csr[j]);
        unsigned long long tv = th[(e0 & 0x1FFFFu) * GS + l];
        float wv = __uint_as_float((e0 & 0xFFFE0000u) >> 1);
        unsigned lo = (unsigned)tv, hi = (unsigned)(tv >> 32);
        float m;
        m = fmaf(wv, __uint_as_float(lo << 16), bf0);          a0 += (m > 0.f) ? m : 0.01f * m;
        m = fmaf(wv, __uint_as_float(lo & 0xffff0000u), bf1);  a1 += (m > 0.f) ? m : 0.01f * m;
        m = fmaf(wv, __uint_as_float(hi << 16), bf2);          a2 += (m > 0.f) ? m : 0.01f * m;
        m = fmaf(wv, __uint_as_float(hi & 0xffff0000u), bf3);  a3 += (m > 0.f) ? m : 0.01f * m;
    }

    int deg = end - beg;
    float iv = deg ? 1.0f / (float)deg : 0.0f;
    unsigned long long tr = th[(size_t)v * GS + l];
    unsigned lo = (unsigned)tr, hi = (unsigned)(tr >> 32);
    float r0 = __uint_as_float(lo << 16) + bf0;
    float r1 = __uint_as_float(lo & 0xffff0000u) + bf1;
    float r2 = __uint_as_float(hi << 16) + bf2;
    float r3 = __uint_as_float(hi & 0xffff0000u) + bf3;
    r0 = (r0 > 0.f) ? r0 : 0.01f * r0;
    r1 = (r1 > 0.f) ? r1 : 0.01f * r1;
    r2 = (r2 > 0.f) ? r2 : 0.01f * r2;
    r3 = (r3 > 0.f) ? r3 : 0.01f * r3;
    float4 st = make_float4(fmaf(a0, iv, r0), fmaf(a1, iv, r1),
                            fmaf(a2, iv, r2), fmaf(a3, iv, r3));
    *(float4*)(h + (size_t)v * FTOT + fo + 4 * l) = st;
}

// ---------------- head ----------------

__global__ LB256 void pool_kernel(const float* __restrict__ h, float* __restrict__ pool, int n) {
    __shared__ float ls[256];
    int f = threadIdx.x & 31;
    int grp = threadIdx.x >> 5;
    int gid = blockIdx.x * (blockDim.x >> 5) + grp;
    int ngrp = (blockDim.x >> 5) * gridDim.x;
    float s = 0.0f;
    for (int v = gid; v < n; v += ngrp) s += h[v * 32 + f];
    ls[threadIdx.x] = s;
    __syncthreads();
    if (threadIdx.x < 32) {
        float tot = 0.0f;
#pragma unroll
        for (int g = 0; g < 8; ++g) tot += ls[g * 32 + threadIdx.x];
        atomicAdd(&pool[threadIdx.x], tot);
    }
}

__global__ void head_kernel(const float* __restrict__ pool, const float* __restrict__ W7,
                            const float* __restrict__ b7, float* __restrict__ out, int n) {
    if (threadIdx.x != 0 || blockIdx.x != 0) return;
    float invn = 1.0f / (float)n;
    float l0 = b7[0], l1 = b7[1];
    for (int f = 0; f < 32; ++f) {
        float p = pool[f] * invn;
        l0 = fmaf(p, W7[f], l0);
        l1 = fmaf(p, W7[32 + f], l1);
    }
    float m = fmaxf(l0, l1);
    float lse = m + logf(expf(l0 - m) + expf(l1 - m));
    out[0] = l0 - lse;
    out[1] = l1 - lse;
}

// ---------------- launch ----------------

extern "C" void kernel_launch(void* const* d_in, const int* in_sizes, int n_in,
                              void* d_out, int out_size, void* d_ws, size_t ws_size,
                              hipStream_t stream) {
    const float* x  = (const float*)d_in[0];
    const int* edge = (const int*)d_in[1];
    const float* w  = (const float*)d_in[2];
    const float* W1 = (const float*)d_in[3];
    const float* b1 = (const float*)d_in[4];
    const float* W3 = (const float*)d_in[5];
    const float* b3 = (const float*)d_in[6];
    const float* W5 = (const float*)d_in[7];
    const float* b5 = (const float*)d_in[8];
    const float* W7 = (const float*)d_in[9];
    const float* b7 = (const float*)d_in[10];
    float* out = (float*)d_out;

    const int N = in_sizes[0] / 4;
    const int E = in_sizes[1] / 2;
    const int* row = edge;
    const int* col = edge + E;

    const int nb = (N + NB_ROWS - 1) >> NB_SHIFT;    // 391 buckets of 256 rows
    const int G = GA;                                // 1024
    const int chunk = (E + G - 1) / G;               // 3125
    const int M = nb * G;                            // ~400k

    char* ws = (char*)d_ws;
    size_t off8 = 0;
    auto alloc = [&](size_t bytes) {
        void* p = ws + off8;
        off8 += (bytes + 255) & ~(size_t)255;
        return p;
    };
    int*      bsum     = (int*)alloc(256 * 4);
    int*      boff     = (int*)alloc(256 * 4);
    int*      countmat = (int*)alloc((size_t)M * 4);
    int*      offm     = (int*)alloc(((size_t)M + 1) * 4);
    int*      rowptr   = (int*)alloc(((size_t)N + 1) * 4);
    float*    pool     = (float*)alloc(32 * 4);
    unsigned* csr      = (unsigned*)alloc((size_t)E * 4);
    __hip_bfloat16* t0 = (__hip_bfloat16*)alloc((size_t)N * 16 * 2);
    __hip_bfloat16* t1 = (__hip_bfloat16*)alloc((size_t)N * 16 * 2);
    float*    h1       = (float*)alloc((size_t)N * 8 * 4);
    float*    h2       = (float*)alloc((size_t)N * 16 * 4);
    // tmp (E*8 = 25.6MB) overlaid with h3 (N*32*4 = 12.8MB): tmp dead before layers
    size_t tmpsz = (size_t)E * 8;
    size_t h3sz  = (size_t)N * 32 * 4;
    char*  big   = (char*)alloc(tmpsz > h3sz ? tmpsz : h3sz);
    unsigned long long* tmp = (unsigned long long*)big;
    float*              h3  = (float*)big;
    (void)ws_size;

    hipMemsetAsync(pool, 0, 32 * 4, stream);

    const int B = 256;
    const int nbkM = (M + 8191) / 8192;  // 49 <= 64 (PT=32)

    // CSR build
    hist_kernel<<<G, B, 0, stream>>>(row, E, nb, chunk, countmat);
    gscan_sum<32><<<nbkM, B, 0, stream>>>(countmat, M, bsum);
    gscan_offsets<<<1, 64, 0, stream>>>(bsum, nbkM, boff);
    gscan_scatter<32><<<nbkM, B, 0, stream>>>(countmat, M, boff, E, offm);
    sort_scatter_kernel<<<G, B, 0, stream>>>(row, col, w, offm, E, G, chunk, tmp);
    csr_build_kernel<<<nb, 512, 0, stream>>>(tmp, offm, G, N, E, rowptr, csr);

    // ---- block 1: 4 -> 8 ----
    transform_kernel<4, 8><<<(N * 8 + B - 1) / B, B, 0, stream>>>(x, W1, t0, t0, N);
    agg_half_kernel<8, 8><<<(N + 127) / 128, B, 0, stream>>>(rowptr, csr, (const unsigned long long*)t0, b1, 0, h1, N);

    // ---- block 2: 8 -> 16 ----
    transform_kernel<8, 16><<<(N * 16 + B - 1) / B, B, 0, stream>>>(h1, W3, t0, t0, N);
    agg_half_kernel<16, 16><<<(N + 63) / 64, B, 0, stream>>>(rowptr, csr, (const unsigned long long*)t0, b3, 0, h2, N);

    // ---- block 3: 16 -> 32 (two independent 16-feature halves) ----
    transform_kernel<16, 32><<<(N * 32 + B - 1) / B, B, 0, stream>>>(h2, W5, t0, t1, N);
    agg_half_kernel<16, 32><<<(N + 63) / 64, B, 0, stream>>>(rowptr, csr, (const unsigned long long*)t0, b5, 0, h3, N);
    agg_half_kernel<16, 32><<<(N + 63) / 64, B, 0, stream>>>(rowptr, csr, (const unsigned long long*)t1, b5, 16, h3, N);

    // ---- head ----
    pool_kernel<<<256, B, 0, stream>>>(h3, pool, N);
    head_kernel<<<1, 64, 0, stream>>>(pool, W7, b7, out, N);
}